// Round 11
// baseline (14299.474 us; speedup 1.0000x reference)
//
#include <hip/hip_runtime.h>
#include <hip/hip_bf16.h>
#include <cstddef>
#include <cstdint>

static constexpr int BB = 16;    // batch
static constexpr int TT = 1024;  // time steps
static constexpr int EE = 512;   // input dim
static constexpr int HH = 1024;  // hidden dim

// scan decomposition: 8 groups x 32 blocks (256 blocks, 1/CU, 1024 thr);
// group owns 2 batches, all cols. Block owns 32 cols x 3 gates.
static constexpr int NG   = 8;
static constexpr int GBLK = 32;
static constexpr int BPG  = 2;
static constexpr int COLS = 32;

using u32 = unsigned int;
typedef float f32x4 __attribute__((ext_vector_type(4)));

// "not yet written" sentinel. h is always finite, so this NaN payload can
// never be produced as a real value.
static constexpr u32 PZ = 0x7FC0DEADu;

// ---------- storage-type helpers (fp32 or bf16 scratch for xr/xz) ----------
__device__ __forceinline__ float st_load(const float* p) { return *p; }
__device__ __forceinline__ float st_load(const __hip_bfloat16* p) { return __bfloat162float(*p); }
__device__ __forceinline__ void st_store(float* p, float v) { *p = v; }
__device__ __forceinline__ void st_store(__hip_bfloat16* p, float v) { *p = __float2bfloat16(v); }

// 16B device-scope (L1/L2-bypassing, LLC-coherent) load.
__device__ __forceinline__ void llc_load(f32x4& d, const f32x4* p) {
    asm volatile("global_load_dwordx4 %0, %1, off sc0 sc1" : "=v"(d) : "v"(p));
}
__device__ __forceinline__ void llc_drain() {
    asm volatile("s_waitcnt vmcnt(0)" ::: "memory");
    __builtin_amdgcn_sched_barrier(0);
}
__device__ __forceinline__ bool ok4(const f32x4 v) {
    return __float_as_uint(v[0]) != PZ && __float_as_uint(v[1]) != PZ &&
           __float_as_uint(v[2]) != PZ && __float_as_uint(v[3]) != PZ;
}

#define FMA4(ACC, S, W)                         \
    (ACC).x = fmaf((S), (W).x, (ACC).x);        \
    (ACC).y = fmaf((S), (W).y, (ACC).y);        \
    (ACC).z = fmaf((S), (W).z, (ACC).z);        \
    (ACC).w = fmaf((S), (W).w, (ACC).w);

// =====================================================================
// Phase 1: xr = x@Wxr+br -> ws, xz = x@Wxz+bz -> ws, xi = x@Wi+b -> d_out
// Also zeroes the scan kernel's barrier counters (block (0,0)).
// =====================================================================
template <typename ST>
__global__ __launch_bounds__(256) void proj_kernel(
    const float* __restrict__ x,
    const float* __restrict__ Wxr, const float* __restrict__ br,
    const float* __restrict__ Wxz, const float* __restrict__ bz,
    const float* __restrict__ Wi,  const float* __restrict__ bi,
    ST* __restrict__ xr_out, ST* __restrict__ xz_out, float* __restrict__ xi_out,
    u32* __restrict__ bar)
{
    __shared__ float xT[16][68];
    __shared__ float wB[3][16][64];

    const int tid = threadIdx.x;
    if (blockIdx.x == 0 && blockIdx.y == 0) bar[tid] = 0u;   // counters in [0,256)

    const int tx = tid & 15, ty = tid >> 4;
    const int m0 = blockIdx.y * 64, n0 = blockIdx.x * 64;
    const float* Wg[3] = {Wxr, Wxz, Wi};

    float4 acc[3][4];
#pragma unroll
    for (int g = 0; g < 3; ++g)
#pragma unroll
        for (int i = 0; i < 4; ++i) acc[g][i] = make_float4(0.f, 0.f, 0.f, 0.f);

    const int xrow = tid >> 2, xk = (tid & 3) * 4;
    const int wk = tid >> 4, wn = (tid & 15) * 4;

    for (int k0 = 0; k0 < EE; k0 += 16) {
        float4 xv = *(const float4*)(x + (size_t)(m0 + xrow) * EE + k0 + xk);
        xT[xk + 0][xrow] = xv.x;
        xT[xk + 1][xrow] = xv.y;
        xT[xk + 2][xrow] = xv.z;
        xT[xk + 3][xrow] = xv.w;
#pragma unroll
        for (int g = 0; g < 3; ++g) {
            float4 wv = *(const float4*)(Wg[g] + (size_t)(k0 + wk) * HH + n0 + wn);
            *(float4*)&wB[g][wk][wn] = wv;
        }
        __syncthreads();
#pragma unroll
        for (int kk = 0; kk < 16; ++kk) {
            float4 a  = *(const float4*)&xT[kk][ty * 4];
            float4 w0 = *(const float4*)&wB[0][kk][tx * 4];
            float4 w1 = *(const float4*)&wB[1][kk][tx * 4];
            float4 w2 = *(const float4*)&wB[2][kk][tx * 4];
            float as[4] = {a.x, a.y, a.z, a.w};
#pragma unroll
            for (int i = 0; i < 4; ++i) {
                FMA4(acc[0][i], as[i], w0);
                FMA4(acc[1][i], as[i], w1);
                FMA4(acc[2][i], as[i], w2);
            }
        }
        __syncthreads();
    }

    float4 bv0 = *(const float4*)(br + n0 + tx * 4);
    float4 bv1 = *(const float4*)(bz + n0 + tx * 4);
    float4 bv2 = *(const float4*)(bi + n0 + tx * 4);
#pragma unroll
    for (int i = 0; i < 4; ++i) {
        size_t m = (size_t)m0 + ty * 4 + i;
        size_t off = m * HH + n0 + tx * 4;
        float4 v0 = acc[0][i]; v0.x += bv0.x; v0.y += bv0.y; v0.z += bv0.z; v0.w += bv0.w;
        float4 v1 = acc[1][i]; v1.x += bv1.x; v1.y += bv1.y; v1.z += bv1.z; v1.w += bv1.w;
        float4 v2 = acc[2][i]; v2.x += bv2.x; v2.y += bv2.y; v2.z += bv2.z; v2.w += bv2.w;
        st_store(xr_out + off + 0, v0.x); st_store(xr_out + off + 1, v0.y);
        st_store(xr_out + off + 2, v0.z); st_store(xr_out + off + 3, v0.w);
        st_store(xz_out + off + 0, v1.x); st_store(xz_out + off + 1, v1.y);
        st_store(xz_out + off + 2, v1.z); st_store(xz_out + off + 3, v1.w);
        *(float4*)(xi_out + off) = v2;
    }
}

// =====================================================================
// DPP all-reduce over each row of 16 lanes (sum). Validated R2-R9.
// =====================================================================
__device__ __forceinline__ float row16_allreduce(float v) {
    int y;
    y = __builtin_amdgcn_update_dpp(0, __float_as_int(v), 0xB1, 0xF, 0xF, true);  // quad_perm [1,0,3,2]
    v += __int_as_float(y);
    y = __builtin_amdgcn_update_dpp(0, __float_as_int(v), 0x4E, 0xF, 0xF, true);  // quad_perm [2,3,0,1]
    v += __int_as_float(y);
    y = __builtin_amdgcn_update_dpp(0, __float_as_int(v), 0x124, 0xF, 0xF, true); // row_ror:4
    v += __int_as_float(y);
    y = __builtin_amdgcn_update_dpp(0, __float_as_int(v), 0x128, 0xF, 0xF, true); // row_ror:8
    v += __int_as_float(y);
    return v;
}

// =====================================================================
// One-time flat per-group barrier (orders init before the main loop).
// =====================================================================
__device__ __forceinline__ void xbar(u32* ctr, unsigned target) {
    __syncthreads();
    if (threadIdx.x == 0) {
        asm volatile("s_waitcnt vmcnt(0)" ::: "memory");
        __builtin_amdgcn_sched_barrier(0);
        __hip_atomic_fetch_add(ctr, 1u, __ATOMIC_RELAXED, __HIP_MEMORY_SCOPE_AGENT);
        while (__hip_atomic_load(ctr, __ATOMIC_RELAXED, __HIP_MEMORY_SCOPE_AGENT) < target) {
            __builtin_amdgcn_s_sleep(1);
        }
        __builtin_amdgcn_sched_barrier(0);
    }
    __syncthreads();
}

// =====================================================================
// Phase 2: persistent barrier-free scan. 8 groups x 32 blocks x 1024 thr
// (16 waves/block = 4 waves/SIMD at 1 block/CU — the known-good 256-block
// cooperative grid). Waves factor as (wu = wv>>3: unit-half, wk = wv&7:
// k-eighth); each wave's internal template is IDENTICAL to R9/R10's
// validated wave: cgg/kslo split, wreg[12][8] fp32, 192 FMA, 24
// row16_allreduce, 1 staged granule/lane, wave-local lgkm sync.
// ugc = wu*48 + cgg*12 + u in [0,96): gate=ugc>>5, col=n0+(ugc&31);
// k = wk*128 + kslo*8 + j. Combine sums the 8 wk-waves of each unit-half.
// Poison protocol identical to R5/R9 (4 rotating epochs, NaN sentinel,
// early re-poison after wave-0 poll success — two-level indirection proof:
// wave0 poll of h_t ok => blocks 0..3 stored h_t => they passed S2@t-1 =>
// their 16 waves polled ALL cols of h_{t-1} => all 32 blocks stored h_{t-1}
// => all passed S2@t-2 => all epoch-(t+2)&3 reads complete).
// =====================================================================
template <typename ST>
__global__ __launch_bounds__(1024, 4) void scan_kernel(
    const ST* __restrict__ xr, const ST* __restrict__ xz,
    const float* __restrict__ Whr, const float* __restrict__ Whz, const float* __restrict__ Wh,
    float* __restrict__ out,      // d_out: xi pre-activations, overwritten with h
    float* __restrict__ hbuf,     // [4][16][1024] fp32 rotating exchange epochs
    u32* __restrict__ bar)
{
    __shared__ f32x4 hsx[16][BPG][32];   // [wave][batch][slot] 16KB, wave-private
    __shared__ float red[16][4][24];     // [wave][cgg][b2*12+u] 6KB
    __shared__ float pre[96][BPG];       // [ugc][b2]

    const int tid = threadIdx.x, bid = blockIdx.x;
    const int lane = tid & 63, wv = tid >> 6;       // wv 0..15
    const int cgg = lane >> 4, kslo = lane & 15;
    const int wu = wv >> 3, wk = wv & 7;            // unit-half, k-eighth
    const int group = bid >> 5, gb = bid & 31;      // group 0..7, 32 blocks
    const int n0 = gb * COLS;
    u32* ctr = bar + group * 32;                    // 128B-separated counters

    // ---- recurrent weights -> registers: 12 units x 8 k ----
    float wreg[12][8];
    {
        const float* WG[3] = {Whr, Whz, Wh};
#pragma unroll
        for (int u = 0; u < 12; ++u) {
            int ugc = wu * 48 + cgg * 12 + u;       // 0..95: gate=ugc>>5, col=ugc&31
            const float* W = WG[ugc >> 5];
            int col = n0 + (ugc & 31);
#pragma unroll
            for (int j = 0; j < 8; ++j)
                wreg[u][j] = W[(size_t)(wk * 128 + kslo * 8 + j) * HH + col];
        }
    }

    const float pzf = __uint_as_float(PZ);
    const int tb2 = tid >> 5, tc = tid & 31;        // elementwise mapping (tid<64)
    const int tbg = group * BPG + tb2;              // global batch
    const int coln = n0 + tc;

    // ---- init: zero B0 (h_0 = 0), poison B1..B3; prefetch t=0 operands ----
    float pxr = 0.f, pxz = 0.f, pxi = 0.f, hprev = 0.f;
    if (tid < 64) {
        float* b0 = hbuf + group * (BPG * HH) + tb2 * HH + coln;
        __hip_atomic_store(b0,         0.f, __ATOMIC_RELAXED, __HIP_MEMORY_SCOPE_AGENT);
        __hip_atomic_store(b0 + 16384, pzf, __ATOMIC_RELAXED, __HIP_MEMORY_SCOPE_AGENT);
        __hip_atomic_store(b0 + 32768, pzf, __ATOMIC_RELAXED, __HIP_MEMORY_SCOPE_AGENT);
        __hip_atomic_store(b0 + 49152, pzf, __ATOMIC_RELAXED, __HIP_MEMORY_SCOPE_AGENT);
        size_t idx0 = (size_t)(tbg * TT) * HH + coln;
        pxr = st_load(xr + idx0); pxz = st_load(xz + idx0); pxi = out[idx0];
    }
    xbar(ctr, GBLK);   // one-time: init visible before anyone polls

    // staging: each lane loads ONE granule of its wave's 32-slot k-window
    // (batch = lane>>5), slot rotated by gb to spread LLC banks. The two
    // unit-half waves sharing wk stage duplicately (wave-private LDS).
    const int b_ld = lane >> 5;                     // 0..1
    const int s_rot = ((lane & 31) + gb) & 31;      // 0..31
    const int g_base = group * (BPG * 256) + b_ld * 256 + wk * 32 + s_rot;

    for (int t = 0; t < TT; ++t) {
        // ---- stage h_t: poll own granule until non-poison, wave-local sync ----
        {
            const f32x4* p = (const f32x4*)hbuf + (size_t)(t & 3) * 4096 + g_base;
            f32x4 va;
            for (;;) {
                llc_load(va, p); llc_drain();
                if (ok4(va)) break;
                __builtin_amdgcn_s_sleep(1);
            }
            hsx[wv][b_ld][s_rot] = va;
            asm volatile("s_waitcnt lgkmcnt(0)" ::: "memory");  // wave-local LDS visibility
            __builtin_amdgcn_sched_barrier(0);
        }

        // ---- early re-poison B(t+2) (validated R6/R9; acks under compute) ----
        if (tid < 64 && t + 2 < TT) {
            __hip_atomic_store(hbuf + (size_t)((t + 2) & 3) * 16384
                               + group * (BPG * HH) + tb2 * HH + coln,
                               pzf, __ATOMIC_RELAXED, __HIP_MEMORY_SCOPE_AGENT);
        }

        // ---- partial dots: 2 batches x 12 units x 8 k = 192 FMA/thread ----
        float pacc[BPG][12];
#pragma unroll
        for (int b = 0; b < BPG; ++b)
#pragma unroll
            for (int u = 0; u < 12; ++u) pacc[b][u] = 0.f;

#pragma unroll
        for (int b = 0; b < BPG; ++b) {
            f32x4 ha = hsx[wv][b][2 * kslo];
            f32x4 hb = hsx[wv][b][2 * kslo + 1];
#pragma unroll
            for (int u = 0; u < 12; ++u) {
                float a = pacc[b][u];
                a = fmaf(ha[0], wreg[u][0], a);
                a = fmaf(ha[1], wreg[u][1], a);
                a = fmaf(ha[2], wreg[u][2], a);
                a = fmaf(ha[3], wreg[u][3], a);
                a = fmaf(hb[0], wreg[u][4], a);
                a = fmaf(hb[1], wreg[u][5], a);
                a = fmaf(hb[2], wreg[u][6], a);
                a = fmaf(hb[3], wreg[u][7], a);
                pacc[b][u] = a;
            }
        }

        // ---- reduce over kslo (16 lanes per row): 24 allreduces ----
#pragma unroll
        for (int b = 0; b < BPG; ++b)
#pragma unroll
            for (int u = 0; u < 12; ++u) pacc[b][u] = row16_allreduce(pacc[b][u]);

        if (kslo == 0) {
#pragma unroll
            for (int b = 0; b < BPG; ++b)
#pragma unroll
                for (int u = 0; u < 12; ++u) red[wv][cgg][b * 12 + u] = pacc[b][u];
        }
        __syncthreads();                 // S1: red ready

        // ---- combine the 8 wk-waves of each unit-half -> 192 pre-acts ----
        if (tid < 192) {
            int b2 = tid & 1, ugc = tid >> 1;        // ugc in [0,96)
            int uh = (ugc >= 48);
            int ug = ugc - uh * 48;                  // [0,48)
            int cq = ug / 12, u = ug - cq * 12;
            float s = 0.f;
#pragma unroll
            for (int w = 0; w < 8; ++w) s += red[uh * 8 + w][cq][b2 * 12 + u];
            pre[ugc][b2] = s;
        }
        __syncthreads();                 // S2: pre ready

        // ---- elementwise GRU update; h-store is the next step's signal ----
        if (tid < 64) {
            float dr = pre[tc][tb2], dz = pre[32 + tc][tb2], dh = pre[64 + tc][tb2];
            float r = 1.f / (1.f + expf(-(dr + pxr)));
            float z = 1.f / (1.f + expf(-(dz + pxz)));
            float cand = tanhf(fmaf(r, dh, pxi));
            float hnew = fmaf(z, hprev - cand, cand);         // z*h + (1-z)*cand
            hprev = hnew;                                     // carried in register
            // drain: orders the (long-acked) early poison before the h-store
            asm volatile("s_waitcnt vmcnt(0)" ::: "memory");
            __builtin_amdgcn_sched_barrier(0);
            if (t + 1 < TT) {
                __hip_atomic_store(hbuf + (size_t)((t + 1) & 3) * 16384
                                   + group * (BPG * HH) + tb2 * HH + coln,
                                   hnew, __ATOMIC_RELAXED, __HIP_MEMORY_SCOPE_AGENT);
            }
            size_t idx = (size_t)(tbg * TT + t) * HH + coln;
            out[idx] = hnew;
            // self-prefetch t+1 operands (off critical path; lands during next step)
            if (t + 1 < TT) {
                size_t idx2 = idx + HH;
                pxr = st_load(xr + idx2); pxz = st_load(xz + idx2); pxi = out[idx2];
            }
        }
        // no block barrier: waves proceed straight to polling h_{t+1}
    }
}

__global__ void sentinel_kernel(float* out) {
    if (threadIdx.x == 0 && blockIdx.x == 0) out[0] = 12345.0f;
}

// =====================================================================
extern "C" void kernel_launch(void* const* d_in, const int* in_sizes, int n_in,
                              void* d_out, int out_size, void* d_ws, size_t ws_size,
                              hipStream_t stream) {
    const float* x   = (const float*)d_in[0];
    const float* Wxr = (const float*)d_in[1];
    const float* Whr = (const float*)d_in[2];
    const float* br  = (const float*)d_in[3];
    const float* Wxz = (const float*)d_in[4];
    const float* Whz = (const float*)d_in[5];
    const float* bz  = (const float*)d_in[6];
    const float* Wi  = (const float*)d_in[7];
    const float* Wh  = (const float*)d_in[8];
    const float* bb  = (const float*)d_in[9];
    float* out = (float*)d_out;

    const size_t BTH = (size_t)BB * TT * HH;
    const size_t HBUF_ELTS = (size_t)4 * BB * HH;      // 4 rotating epochs
    const size_t BAR_BYTES = 4096;
    const size_t need_f32 = 2 * BTH * sizeof(float) + HBUF_ELTS * sizeof(float) + BAR_BYTES;
    const size_t need_b16 = 2 * BTH * sizeof(__hip_bfloat16) + HBUF_ELTS * sizeof(float) + BAR_BYTES;

    dim3 pgrid(HH / 64, (BB * TT) / 64);   // (16, 256)
    dim3 sgrid(NG * GBLK);                 // 256 blocks, 1 per CU

    if (ws_size >= need_f32) {
        float* xr = (float*)d_ws;
        float* xz = xr + BTH;
        float* hb = xz + BTH;
        u32* bar = (u32*)(hb + HBUF_ELTS);
        proj_kernel<float><<<pgrid, 256, 0, stream>>>(x, Wxr, br, Wxz, bz, Wi, bb, xr, xz, out, bar);
        const float* xrc = xr; const float* xzc = xz;
        void* args[8] = {(void*)&xrc, (void*)&xzc, (void*)&Whr, (void*)&Whz,
                         (void*)&Wh, (void*)&out, (void*)&hb, (void*)&bar};
        hipLaunchCooperativeKernel((void*)scan_kernel<float>, sgrid, dim3(1024),
                                   args, 0, stream);
    } else if (ws_size >= need_b16) {
        __hip_bfloat16* xr = (__hip_bfloat16*)d_ws;
        __hip_bfloat16* xz = xr + BTH;
        float* hb = (float*)(xz + BTH);
        u32* bar = (u32*)(hb + HBUF_ELTS);
        proj_kernel<__hip_bfloat16><<<pgrid, 256, 0, stream>>>(x, Wxr, br, Wxz, bz, Wi, bb, xr, xz, out, bar);
        const __hip_bfloat16* xrc = xr; const __hip_bfloat16* xzc = xz;
        void* args[8] = {(void*)&xrc, (void*)&xzc, (void*)&Whr, (void*)&Whz,
                         (void*)&Wh, (void*)&out, (void*)&hb, (void*)&bar};
        hipLaunchCooperativeKernel((void*)scan_kernel<__hip_bfloat16>, sgrid, dim3(1024),
                                   args, 0, stream);
    } else {
        sentinel_kernel<<<1, 64, 0, stream>>>(out);
    }
}

// Round 12
// 5554.934 us; speedup vs baseline: 2.5742x; 2.5742x over previous
//
#include <hip/hip_runtime.h>
#include <hip/hip_bf16.h>
#include <cstddef>
#include <cstdint>

static constexpr int BB = 16;    // batch
static constexpr int TT = 1024;  // time steps
static constexpr int EE = 512;   // input dim
static constexpr int HH = 1024;  // hidden dim

// scan decomposition: 8 groups x 32 blocks (256 blocks, 1/CU, 1024 thr);
// group owns 2 batches, all cols. Block owns 32 cols x 3 gates.
static constexpr int NG   = 8;
static constexpr int GBLK = 32;
static constexpr int BPG  = 2;
static constexpr int COLS = 32;

using u32 = unsigned int;
typedef float f32x4 __attribute__((ext_vector_type(4)));

// "not yet written" sentinel. h is always finite, so this NaN payload can
// never be produced as a real value.
static constexpr u32 PZ = 0x7FC0DEADu;

// ---------- storage-type helpers (fp32 or bf16 scratch for xr/xz) ----------
__device__ __forceinline__ float st_load(const float* p) { return *p; }
__device__ __forceinline__ float st_load(const __hip_bfloat16* p) { return __bfloat162float(*p); }
__device__ __forceinline__ void st_store(float* p, float v) { *p = v; }
__device__ __forceinline__ void st_store(__hip_bfloat16* p, float v) { *p = __float2bfloat16(v); }

// 16B device-scope (L1/L2-bypassing, LLC-coherent) load.
__device__ __forceinline__ void llc_load(f32x4& d, const f32x4* p) {
    asm volatile("global_load_dwordx4 %0, %1, off sc0 sc1" : "=v"(d) : "v"(p));
}
__device__ __forceinline__ void llc_drain() {
    asm volatile("s_waitcnt vmcnt(0)" ::: "memory");
    __builtin_amdgcn_sched_barrier(0);
}
__device__ __forceinline__ bool ok4(const f32x4 v) {
    return __float_as_uint(v[0]) != PZ && __float_as_uint(v[1]) != PZ &&
           __float_as_uint(v[2]) != PZ && __float_as_uint(v[3]) != PZ;
}

#define FMA4(ACC, S, W)                         \
    (ACC).x = fmaf((S), (W).x, (ACC).x);        \
    (ACC).y = fmaf((S), (W).y, (ACC).y);        \
    (ACC).z = fmaf((S), (W).z, (ACC).z);        \
    (ACC).w = fmaf((S), (W).w, (ACC).w);

// =====================================================================
// Phase 1: xr = x@Wxr+br -> ws, xz = x@Wxz+bz -> ws, xi = x@Wi+b -> d_out
// Also zeroes the scan kernel's barrier counters (block (0,0)).
// =====================================================================
template <typename ST>
__global__ __launch_bounds__(256) void proj_kernel(
    const float* __restrict__ x,
    const float* __restrict__ Wxr, const float* __restrict__ br,
    const float* __restrict__ Wxz, const float* __restrict__ bz,
    const float* __restrict__ Wi,  const float* __restrict__ bi,
    ST* __restrict__ xr_out, ST* __restrict__ xz_out, float* __restrict__ xi_out,
    u32* __restrict__ bar)
{
    __shared__ float xT[16][68];
    __shared__ float wB[3][16][64];

    const int tid = threadIdx.x;
    if (blockIdx.x == 0 && blockIdx.y == 0) bar[tid] = 0u;   // counters in [0,256)

    const int tx = tid & 15, ty = tid >> 4;
    const int m0 = blockIdx.y * 64, n0 = blockIdx.x * 64;
    const float* Wg[3] = {Wxr, Wxz, Wi};

    float4 acc[3][4];
#pragma unroll
    for (int g = 0; g < 3; ++g)
#pragma unroll
        for (int i = 0; i < 4; ++i) acc[g][i] = make_float4(0.f, 0.f, 0.f, 0.f);

    const int xrow = tid >> 2, xk = (tid & 3) * 4;
    const int wk = tid >> 4, wn = (tid & 15) * 4;

    for (int k0 = 0; k0 < EE; k0 += 16) {
        float4 xv = *(const float4*)(x + (size_t)(m0 + xrow) * EE + k0 + xk);
        xT[xk + 0][xrow] = xv.x;
        xT[xk + 1][xrow] = xv.y;
        xT[xk + 2][xrow] = xv.z;
        xT[xk + 3][xrow] = xv.w;
#pragma unroll
        for (int g = 0; g < 3; ++g) {
            float4 wv = *(const float4*)(Wg[g] + (size_t)(k0 + wk) * HH + n0 + wn);
            *(float4*)&wB[g][wk][wn] = wv;
        }
        __syncthreads();
#pragma unroll
        for (int kk = 0; kk < 16; ++kk) {
            float4 a  = *(const float4*)&xT[kk][ty * 4];
            float4 w0 = *(const float4*)&wB[0][kk][tx * 4];
            float4 w1 = *(const float4*)&wB[1][kk][tx * 4];
            float4 w2 = *(const float4*)&wB[2][kk][tx * 4];
            float as[4] = {a.x, a.y, a.z, a.w};
#pragma unroll
            for (int i = 0; i < 4; ++i) {
                FMA4(acc[0][i], as[i], w0);
                FMA4(acc[1][i], as[i], w1);
                FMA4(acc[2][i], as[i], w2);
            }
        }
        __syncthreads();
    }

    float4 bv0 = *(const float4*)(br + n0 + tx * 4);
    float4 bv1 = *(const float4*)(bz + n0 + tx * 4);
    float4 bv2 = *(const float4*)(bi + n0 + tx * 4);
#pragma unroll
    for (int i = 0; i < 4; ++i) {
        size_t m = (size_t)m0 + ty * 4 + i;
        size_t off = m * HH + n0 + tx * 4;
        float4 v0 = acc[0][i]; v0.x += bv0.x; v0.y += bv0.y; v0.z += bv0.z; v0.w += bv0.w;
        float4 v1 = acc[1][i]; v1.x += bv1.x; v1.y += bv1.y; v1.z += bv1.z; v1.w += bv1.w;
        float4 v2 = acc[2][i]; v2.x += bv2.x; v2.y += bv2.y; v2.z += bv2.z; v2.w += bv2.w;
        st_store(xr_out + off + 0, v0.x); st_store(xr_out + off + 1, v0.y);
        st_store(xr_out + off + 2, v0.z); st_store(xr_out + off + 3, v0.w);
        st_store(xz_out + off + 0, v1.x); st_store(xz_out + off + 1, v1.y);
        st_store(xz_out + off + 2, v1.z); st_store(xz_out + off + 3, v1.w);
        *(float4*)(xi_out + off) = v2;
    }
}

// =====================================================================
// DPP all-reduce over each row of 16 lanes (sum). Validated R2-R11.
// =====================================================================
__device__ __forceinline__ float row16_allreduce(float v) {
    int y;
    y = __builtin_amdgcn_update_dpp(0, __float_as_int(v), 0xB1, 0xF, 0xF, true);  // quad_perm [1,0,3,2]
    v += __int_as_float(y);
    y = __builtin_amdgcn_update_dpp(0, __float_as_int(v), 0x4E, 0xF, 0xF, true);  // quad_perm [2,3,0,1]
    v += __int_as_float(y);
    y = __builtin_amdgcn_update_dpp(0, __float_as_int(v), 0x124, 0xF, 0xF, true); // row_ror:4
    v += __int_as_float(y);
    y = __builtin_amdgcn_update_dpp(0, __float_as_int(v), 0x128, 0xF, 0xF, true); // row_ror:8
    v += __int_as_float(y);
    return v;
}

// =====================================================================
// One-time flat per-group barrier (orders init before the main loop).
// =====================================================================
__device__ __forceinline__ void xbar(u32* ctr, unsigned target) {
    __syncthreads();
    if (threadIdx.x == 0) {
        asm volatile("s_waitcnt vmcnt(0)" ::: "memory");
        __builtin_amdgcn_sched_barrier(0);
        __hip_atomic_fetch_add(ctr, 1u, __ATOMIC_RELAXED, __HIP_MEMORY_SCOPE_AGENT);
        while (__hip_atomic_load(ctr, __ATOMIC_RELAXED, __HIP_MEMORY_SCOPE_AGENT) < target) {
            __builtin_amdgcn_s_sleep(1);
        }
        __builtin_amdgcn_sched_barrier(0);
    }
    __syncthreads();
}

// =====================================================================
// Phase 2: persistent barrier-free scan. 8 groups x 32 blocks x 1024 thr
// (16 waves = 4 waves/SIMD at 1 block/CU — the coop grid R11 proved
// launches). R12 changes vs R11, both register-budget fixes after R11's
// spill catastrophe (VGPR=64, wreg in scratch, 37GB fetched):
//   (a) __launch_bounds__(1024) with NO second arg -> allocator cap 128.
//   (b) waves factor 4 unit-quarters (wq) x 4 k-quarters (wk); lane holds
//       wreg[6][16] (96 f32, same total) but processes the 2 batches
//       SEQUENTIALLY through reduce: live pacc 24 -> 6.
// Per-thread work unchanged: 192 FMA, 12 allreduces, 2 staged granules.
// Combine sums the 4 wk-waves of each unit-quarter.
// Poison protocol identical to R5/R9/R11 (4 rotating NaN-sentinel epochs,
// early re-poison after poll success, vmcnt(0) drain before h-store).
// =====================================================================
template <typename ST>
__global__ __launch_bounds__(1024) void scan_kernel(
    const ST* __restrict__ xr, const ST* __restrict__ xz,
    const float* __restrict__ Whr, const float* __restrict__ Whz, const float* __restrict__ Wh,
    float* __restrict__ out,      // d_out: xi pre-activations, overwritten with h
    float* __restrict__ hbuf,     // [4][16][1024] fp32 rotating exchange epochs
    u32* __restrict__ bar)
{
    __shared__ f32x4 hsx[16][BPG][64];   // [wave][batch][slot] 32KB, wave-private
    __shared__ float red[16][4][12];     // [wave][cgg][b2*6+u] 3KB
    __shared__ float pre[96][BPG];       // [ugc][b2]

    const int tid = threadIdx.x, bid = blockIdx.x;
    const int lane = tid & 63, wv = tid >> 6;       // wv 0..15
    const int cgg = lane >> 4, kslo = lane & 15;
    const int wq = wv >> 2, wk = wv & 3;            // unit-quarter, k-quarter
    const int group = bid >> 5, gb = bid & 31;      // group 0..7, 32 blocks
    const int n0 = gb * COLS;
    u32* ctr = bar + group * 32;                    // 128B-separated counters

    // ---- recurrent weights -> registers: 6 units x 16 k = 96 f32 ----
    float wreg[6][16];
    {
        const float* WG[3] = {Whr, Whz, Wh};
#pragma unroll
        for (int u = 0; u < 6; ++u) {
            int ugc = wq * 24 + cgg * 6 + u;        // 0..95: gate=ugc>>5, col=ugc&31
            const float* W = WG[ugc >> 5];
            int col = n0 + (ugc & 31);
#pragma unroll
            for (int j = 0; j < 16; ++j)
                wreg[u][j] = W[(size_t)(wk * 256 + kslo * 16 + j) * HH + col];
        }
    }

    const float pzf = __uint_as_float(PZ);
    const int tb2 = tid >> 5, tc = tid & 31;        // elementwise mapping (tid<64)
    const int tbg = group * BPG + tb2;              // global batch
    const int coln = n0 + tc;

    // ---- init: zero B0 (h_0 = 0), poison B1..B3; prefetch t=0 operands ----
    float pxr = 0.f, pxz = 0.f, pxi = 0.f, hprev = 0.f;
    if (tid < 64) {
        float* b0 = hbuf + group * (BPG * HH) + tb2 * HH + coln;
        __hip_atomic_store(b0,         0.f, __ATOMIC_RELAXED, __HIP_MEMORY_SCOPE_AGENT);
        __hip_atomic_store(b0 + 16384, pzf, __ATOMIC_RELAXED, __HIP_MEMORY_SCOPE_AGENT);
        __hip_atomic_store(b0 + 32768, pzf, __ATOMIC_RELAXED, __HIP_MEMORY_SCOPE_AGENT);
        __hip_atomic_store(b0 + 49152, pzf, __ATOMIC_RELAXED, __HIP_MEMORY_SCOPE_AGENT);
        size_t idx0 = (size_t)(tbg * TT) * HH + coln;
        pxr = st_load(xr + idx0); pxz = st_load(xz + idx0); pxi = out[idx0];
    }
    xbar(ctr, GBLK);   // one-time: init visible before anyone polls

    // staging: lane loads granule pair (s_rot, s_rot+1) of its wave's
    // 64-granule k-window (batch = lane>>5), rotated by gb.
    const int b_ld = lane >> 5;                     // 0..1
    const int s_rot = ((2 * (lane & 31)) + 2 * gb) & 63;   // even, in [0,64)
    const int g_base = group * (BPG * 256) + b_ld * 256 + wk * 64 + s_rot;

    for (int t = 0; t < TT; ++t) {
        // ---- stage h_t: poll own granules until non-poison, wave-local sync ----
        {
            const f32x4* p = (const f32x4*)hbuf + (size_t)(t & 3) * 4096 + g_base;
            f32x4 va, vb;
            for (;;) {
                llc_load(va, p); llc_load(vb, p + 1); llc_drain();
                if (ok4(va) && ok4(vb)) break;
                __builtin_amdgcn_s_sleep(1);
            }
            hsx[wv][b_ld][s_rot]     = va;
            hsx[wv][b_ld][s_rot + 1] = vb;
            asm volatile("s_waitcnt lgkmcnt(0)" ::: "memory");  // wave-local LDS visibility
            __builtin_amdgcn_sched_barrier(0);
        }

        // ---- early re-poison B(t+2) (validated R6/R9; acks under compute) ----
        if (tid < 64 && t + 2 < TT) {
            __hip_atomic_store(hbuf + (size_t)((t + 2) & 3) * 16384
                               + group * (BPG * HH) + tb2 * HH + coln,
                               pzf, __ATOMIC_RELAXED, __HIP_MEMORY_SCOPE_AGENT);
        }

        // ---- dots, batches SEQUENTIAL (live pacc = 6): 192 FMA/thread ----
#pragma unroll
        for (int b = 0; b < BPG; ++b) {
            float p6[6] = {0.f, 0.f, 0.f, 0.f, 0.f, 0.f};
#pragma unroll
            for (int jj = 0; jj < 4; ++jj) {
                f32x4 h4 = hsx[wv][b][kslo * 4 + jj];
#pragma unroll
                for (int u = 0; u < 6; ++u) {
                    p6[u] = fmaf(h4[0], wreg[u][jj * 4 + 0], p6[u]);
                    p6[u] = fmaf(h4[1], wreg[u][jj * 4 + 1], p6[u]);
                    p6[u] = fmaf(h4[2], wreg[u][jj * 4 + 2], p6[u]);
                    p6[u] = fmaf(h4[3], wreg[u][jj * 4 + 3], p6[u]);
                }
            }
            // reduce over kslo (16 lanes per row): 6 allreduces per batch
#pragma unroll
            for (int u = 0; u < 6; ++u) p6[u] = row16_allreduce(p6[u]);
            if (kslo == 0) {
#pragma unroll
                for (int u = 0; u < 6; ++u) red[wv][cgg][b * 6 + u] = p6[u];
            }
        }
        __syncthreads();                 // S1: red ready

        // ---- combine the 4 wk-waves of each unit-quarter -> 192 pre-acts ----
        if (tid < 192) {
            int b2 = tid & 1, ugc = tid >> 1;        // ugc in [0,96)
            int q = ugc / 24, rem = ugc - q * 24;
            int cq = rem / 6, u = rem - cq * 6;
            float s = red[q * 4 + 0][cq][b2 * 6 + u] + red[q * 4 + 1][cq][b2 * 6 + u]
                    + red[q * 4 + 2][cq][b2 * 6 + u] + red[q * 4 + 3][cq][b2 * 6 + u];
            pre[ugc][b2] = s;
        }
        __syncthreads();                 // S2: pre ready

        // ---- elementwise GRU update; h-store is the next step's signal ----
        if (tid < 64) {
            float dr = pre[tc][tb2], dz = pre[32 + tc][tb2], dh = pre[64 + tc][tb2];
            float r = 1.f / (1.f + expf(-(dr + pxr)));
            float z = 1.f / (1.f + expf(-(dz + pxz)));
            float cand = tanhf(fmaf(r, dh, pxi));
            float hnew = fmaf(z, hprev - cand, cand);         // z*h + (1-z)*cand
            hprev = hnew;                                     // carried in register
            // drain: orders the (long-acked) early poison before the h-store
            asm volatile("s_waitcnt vmcnt(0)" ::: "memory");
            __builtin_amdgcn_sched_barrier(0);
            if (t + 1 < TT) {
                __hip_atomic_store(hbuf + (size_t)((t + 1) & 3) * 16384
                                   + group * (BPG * HH) + tb2 * HH + coln,
                                   hnew, __ATOMIC_RELAXED, __HIP_MEMORY_SCOPE_AGENT);
            }
            size_t idx = (size_t)(tbg * TT + t) * HH + coln;
            out[idx] = hnew;
            // self-prefetch t+1 operands (off critical path; lands during next step)
            if (t + 1 < TT) {
                size_t idx2 = idx + HH;
                pxr = st_load(xr + idx2); pxz = st_load(xz + idx2); pxi = out[idx2];
            }
        }
        // no block barrier: waves proceed straight to polling h_{t+1}
    }
}

__global__ void sentinel_kernel(float* out) {
    if (threadIdx.x == 0 && blockIdx.x == 0) out[0] = 12345.0f;
}

// =====================================================================
extern "C" void kernel_launch(void* const* d_in, const int* in_sizes, int n_in,
                              void* d_out, int out_size, void* d_ws, size_t ws_size,
                              hipStream_t stream) {
    const float* x   = (const float*)d_in[0];
    const float* Wxr = (const float*)d_in[1];
    const float* Whr = (const float*)d_in[2];
    const float* br  = (const float*)d_in[3];
    const float* Wxz = (const float*)d_in[4];
    const float* Whz = (const float*)d_in[5];
    const float* bz  = (const float*)d_in[6];
    const float* Wi  = (const float*)d_in[7];
    const float* Wh  = (const float*)d_in[8];
    const float* bb  = (const float*)d_in[9];
    float* out = (float*)d_out;

    const size_t BTH = (size_t)BB * TT * HH;
    const size_t HBUF_ELTS = (size_t)4 * BB * HH;      // 4 rotating epochs
    const size_t BAR_BYTES = 4096;
    const size_t need_f32 = 2 * BTH * sizeof(float) + HBUF_ELTS * sizeof(float) + BAR_BYTES;
    const size_t need_b16 = 2 * BTH * sizeof(__hip_bfloat16) + HBUF_ELTS * sizeof(float) + BAR_BYTES;

    dim3 pgrid(HH / 64, (BB * TT) / 64);   // (16, 256)
    dim3 sgrid(NG * GBLK);                 // 256 blocks, 1 per CU

    if (ws_size >= need_f32) {
        float* xr = (float*)d_ws;
        float* xz = xr + BTH;
        float* hb = xz + BTH;
        u32* bar = (u32*)(hb + HBUF_ELTS);
        proj_kernel<float><<<pgrid, 256, 0, stream>>>(x, Wxr, br, Wxz, bz, Wi, bb, xr, xz, out, bar);
        const float* xrc = xr; const float* xzc = xz;
        void* args[8] = {(void*)&xrc, (void*)&xzc, (void*)&Whr, (void*)&Whz,
                         (void*)&Wh, (void*)&out, (void*)&hb, (void*)&bar};
        hipLaunchCooperativeKernel((void*)scan_kernel<float>, sgrid, dim3(1024),
                                   args, 0, stream);
    } else if (ws_size >= need_b16) {
        __hip_bfloat16* xr = (__hip_bfloat16*)d_ws;
        __hip_bfloat16* xz = xr + BTH;
        float* hb = (float*)(xz + BTH);
        u32* bar = (u32*)(hb + HBUF_ELTS);
        proj_kernel<__hip_bfloat16><<<pgrid, 256, 0, stream>>>(x, Wxr, br, Wxz, bz, Wi, bb, xr, xz, out, bar);
        const __hip_bfloat16* xrc = xr; const __hip_bfloat16* xzc = xz;
        void* args[8] = {(void*)&xrc, (void*)&xzc, (void*)&Whr, (void*)&Whz,
                         (void*)&Wh, (void*)&out, (void*)&hb, (void*)&bar};
        hipLaunchCooperativeKernel((void*)scan_kernel<__hip_bfloat16>, sgrid, dim3(1024),
                                   args, 0, stream);
    } else {
        sentinel_kernel<<<1, 64, 0, stream>>>(out);
    }
}

// Round 13
// 5184.127 us; speedup vs baseline: 2.7583x; 1.0715x over previous
//
#include <hip/hip_runtime.h>
#include <hip/hip_bf16.h>
#include <cstddef>
#include <cstdint>

static constexpr int BB = 16;    // batch
static constexpr int TT = 1024;  // time steps
static constexpr int EE = 512;   // input dim
static constexpr int HH = 1024;  // hidden dim

// scan decomposition: 4 groups x 64 blocks; group owns 4 batches, all cols.
static constexpr int NG   = 4;
static constexpr int GBLK = 64;
static constexpr int BPG  = 4;
static constexpr int COLS = 16;

using u32 = unsigned int;
typedef float f32x4 __attribute__((ext_vector_type(4)));

// "not yet written" sentinel. h is always finite, so this NaN payload can
// never be produced as a real value.
static constexpr u32 PZ = 0x7FC0DEADu;

// ---------- storage-type helpers (fp32 or bf16 scratch for xr/xz) ----------
__device__ __forceinline__ float st_load(const float* p) { return *p; }
__device__ __forceinline__ float st_load(const __hip_bfloat16* p) { return __bfloat162float(*p); }
__device__ __forceinline__ void st_store(float* p, float v) { *p = v; }
__device__ __forceinline__ void st_store(__hip_bfloat16* p, float v) { *p = __float2bfloat16(v); }

// 16B device-scope (L1/L2-bypassing, LLC-coherent) load.
__device__ __forceinline__ void llc_load(f32x4& d, const f32x4* p) {
    asm volatile("global_load_dwordx4 %0, %1, off sc0 sc1" : "=v"(d) : "v"(p));
}
__device__ __forceinline__ void llc_drain() {
    asm volatile("s_waitcnt vmcnt(0)" ::: "memory");
    __builtin_amdgcn_sched_barrier(0);
}
__device__ __forceinline__ bool ok4(const f32x4 v) {
    return __float_as_uint(v[0]) != PZ && __float_as_uint(v[1]) != PZ &&
           __float_as_uint(v[2]) != PZ && __float_as_uint(v[3]) != PZ;
}

// padded LDS slot map: +1 granule of pad per 8 granules. For even s,
// PS(s+1) == PS(s)+1, so pairwise writes stay contiguous; stride-2 reads
// cover all 8 bank-groups (2-way aliasing = free).
__device__ __forceinline__ int PS(int s) { return s + (s >> 3); }

#define FMA4(ACC, S, W)                         \
    (ACC).x = fmaf((S), (W).x, (ACC).x);        \
    (ACC).y = fmaf((S), (W).y, (ACC).y);        \
    (ACC).z = fmaf((S), (W).z, (ACC).z);        \
    (ACC).w = fmaf((S), (W).w, (ACC).w);

// =====================================================================
// Phase 1: xr = x@Wxr+br -> ws, xz = x@Wxz+bz -> ws, xi = x@Wi+b -> d_out
// Also zeroes the scan kernel's barrier counters (block (0,0)).
// =====================================================================
template <typename ST>
__global__ __launch_bounds__(256) void proj_kernel(
    const float* __restrict__ x,
    const float* __restrict__ Wxr, const float* __restrict__ br,
    const float* __restrict__ Wxz, const float* __restrict__ bz,
    const float* __restrict__ Wi,  const float* __restrict__ bi,
    ST* __restrict__ xr_out, ST* __restrict__ xz_out, float* __restrict__ xi_out,
    u32* __restrict__ bar)
{
    __shared__ float xT[16][68];
    __shared__ float wB[3][16][64];

    const int tid = threadIdx.x;
    if (blockIdx.x == 0 && blockIdx.y == 0) bar[tid] = 0u;

    const int tx = tid & 15, ty = tid >> 4;
    const int m0 = blockIdx.y * 64, n0 = blockIdx.x * 64;
    const float* Wg[3] = {Wxr, Wxz, Wi};

    float4 acc[3][4];
#pragma unroll
    for (int g = 0; g < 3; ++g)
#pragma unroll
        for (int i = 0; i < 4; ++i) acc[g][i] = make_float4(0.f, 0.f, 0.f, 0.f);

    const int xrow = tid >> 2, xk = (tid & 3) * 4;
    const int wk = tid >> 4, wn = (tid & 15) * 4;

    for (int k0 = 0; k0 < EE; k0 += 16) {
        float4 xv = *(const float4*)(x + (size_t)(m0 + xrow) * EE + k0 + xk);
        xT[xk + 0][xrow] = xv.x;
        xT[xk + 1][xrow] = xv.y;
        xT[xk + 2][xrow] = xv.z;
        xT[xk + 3][xrow] = xv.w;
#pragma unroll
        for (int g = 0; g < 3; ++g) {
            float4 wv = *(const float4*)(Wg[g] + (size_t)(k0 + wk) * HH + n0 + wn);
            *(float4*)&wB[g][wk][wn] = wv;
        }
        __syncthreads();
#pragma unroll
        for (int kk = 0; kk < 16; ++kk) {
            float4 a  = *(const float4*)&xT[kk][ty * 4];
            float4 w0 = *(const float4*)&wB[0][kk][tx * 4];
            float4 w1 = *(const float4*)&wB[1][kk][tx * 4];
            float4 w2 = *(const float4*)&wB[2][kk][tx * 4];
            float as[4] = {a.x, a.y, a.z, a.w};
#pragma unroll
            for (int i = 0; i < 4; ++i) {
                FMA4(acc[0][i], as[i], w0);
                FMA4(acc[1][i], as[i], w1);
                FMA4(acc[2][i], as[i], w2);
            }
        }
        __syncthreads();
    }

    float4 bv0 = *(const float4*)(br + n0 + tx * 4);
    float4 bv1 = *(const float4*)(bz + n0 + tx * 4);
    float4 bv2 = *(const float4*)(bi + n0 + tx * 4);
#pragma unroll
    for (int i = 0; i < 4; ++i) {
        size_t m = (size_t)m0 + ty * 4 + i;
        size_t off = m * HH + n0 + tx * 4;
        float4 v0 = acc[0][i]; v0.x += bv0.x; v0.y += bv0.y; v0.z += bv0.z; v0.w += bv0.w;
        float4 v1 = acc[1][i]; v1.x += bv1.x; v1.y += bv1.y; v1.z += bv1.z; v1.w += bv1.w;
        float4 v2 = acc[2][i]; v2.x += bv2.x; v2.y += bv2.y; v2.z += bv2.z; v2.w += bv2.w;
        st_store(xr_out + off + 0, v0.x); st_store(xr_out + off + 1, v0.y);
        st_store(xr_out + off + 2, v0.z); st_store(xr_out + off + 3, v0.w);
        st_store(xz_out + off + 0, v1.x); st_store(xz_out + off + 1, v1.y);
        st_store(xz_out + off + 2, v1.z); st_store(xz_out + off + 3, v1.w);
        *(float4*)(xi_out + off) = v2;
    }
}

// =====================================================================
// DPP all-reduce over each row of 16 lanes (sum). Validated R2-R12.
// =====================================================================
__device__ __forceinline__ float row16_allreduce(float v) {
    int y;
    y = __builtin_amdgcn_update_dpp(0, __float_as_int(v), 0xB1, 0xF, 0xF, true);  // quad_perm [1,0,3,2]
    v += __int_as_float(y);
    y = __builtin_amdgcn_update_dpp(0, __float_as_int(v), 0x4E, 0xF, 0xF, true);  // quad_perm [2,3,0,1]
    v += __int_as_float(y);
    y = __builtin_amdgcn_update_dpp(0, __float_as_int(v), 0x124, 0xF, 0xF, true); // row_ror:4
    v += __int_as_float(y);
    y = __builtin_amdgcn_update_dpp(0, __float_as_int(v), 0x128, 0xF, 0xF, true); // row_ror:8
    v += __int_as_float(y);
    return v;
}

// =====================================================================
// One-time flat per-group barrier (orders init before the main loop).
// =====================================================================
__device__ __forceinline__ void xbar(u32* ctr, unsigned target) {
    __syncthreads();
    if (threadIdx.x == 0) {
        asm volatile("s_waitcnt vmcnt(0)" ::: "memory");
        __builtin_amdgcn_sched_barrier(0);
        __hip_atomic_fetch_add(ctr, 1u, __ATOMIC_RELAXED, __HIP_MEMORY_SCOPE_AGENT);
        while (__hip_atomic_load(ctr, __ATOMIC_RELAXED, __HIP_MEMORY_SCOPE_AGENT) < target) {
            __builtin_amdgcn_s_sleep(1);
        }
        __builtin_amdgcn_sched_barrier(0);
    }
    __syncthreads();
}

// =====================================================================
// Phase 2: persistent barrier-free scan — R9's validated structure (512
// thr, VGPR=108, 4.67us/step) with three attributable edits:
//  (1) padded hsx slots (PS): stride-2 compute reads go 4-way -> 2-way/free.
//  (2) combine/S2 REMOVED: the 64 tail threads read red[] directly (24 LDS
//      reads + 21 adds each); waves 1-7 start polling t+1 one barrier
//      earlier. S1 is now the only per-step __syncthreads.
//  (3) red[] parity-double-buffered: wave w's red-write@t+1 (which can
//      happen before the tail finishes reading red@t, since S2 is gone)
//      targets the other parity buffer — race closed structurally.
// Everything else (poison epochs, early re-poison, staging, weights,
// reduce, tail math) is byte-identical to R9.
// =====================================================================
template <typename ST>
__global__ __launch_bounds__(512, 1) void scan_kernel(
    const ST* __restrict__ xr, const ST* __restrict__ xz,
    const float* __restrict__ Whr, const float* __restrict__ Whz, const float* __restrict__ Wh,
    float* __restrict__ out,      // d_out: xi pre-activations, overwritten with h
    float* __restrict__ hbuf,     // [4][16][1024] fp32 rotating exchange epochs
    u32* __restrict__ bar)
{
    __shared__ f32x4 hsx[8][4][36];      // [wave][batch][padded slot] 18KB
    __shared__ float red[2][8][4][48];   // [parity][wave][cgg][b4*12+u] 12KB

    const int tid = threadIdx.x, bid = blockIdx.x;
    const int lane = tid & 63, wv = tid >> 6;       // wv 0..7
    const int cgg = lane >> 4, kslo = lane & 15;
    const int ks = wv * 16 + kslo;                  // 0..127
    const int group = bid >> 6, gb = bid & 63;
    const int n0 = gb * COLS;
    u32* ctr = bar + group * 64;

    // ---- recurrent weights -> registers: 12 units x 8 k ----
    float wreg[12][8];
    {
        const float* WG[3] = {Whr, Whz, Wh};
#pragma unroll
        for (int u = 0; u < 12; ++u) {
            int ugc = cgg * 12 + u;                 // 0..47: gate=ugc>>4, col=ugc&15
            const float* W = WG[ugc >> 4];
            int col = n0 + (ugc & 15);
#pragma unroll
            for (int j = 0; j < 8; ++j)
                wreg[u][j] = W[(size_t)(ks * 8 + j) * HH + col];
        }
    }

    const float pzf = __uint_as_float(PZ);
    const int tb4 = tid >> 4, tc = tid & 15;        // elementwise mapping (tid<64)
    const int tbg = group * BPG + tb4;
    const int coln = n0 + tc;

    // ---- init: zero B0 (h_0 = 0), poison B1..B3; prefetch t=0 operands ----
    float pxr = 0.f, pxz = 0.f, pxi = 0.f, hprev = 0.f;
    if (tid < 64) {
        float* b0 = hbuf + group * (BPG * HH) + tb4 * HH + coln;
        __hip_atomic_store(b0,         0.f, __ATOMIC_RELAXED, __HIP_MEMORY_SCOPE_AGENT);
        __hip_atomic_store(b0 + 16384, pzf, __ATOMIC_RELAXED, __HIP_MEMORY_SCOPE_AGENT);
        __hip_atomic_store(b0 + 32768, pzf, __ATOMIC_RELAXED, __HIP_MEMORY_SCOPE_AGENT);
        __hip_atomic_store(b0 + 49152, pzf, __ATOMIC_RELAXED, __HIP_MEMORY_SCOPE_AGENT);
        size_t idx0 = (size_t)(tbg * TT) * HH + coln;
        pxr = st_load(xr + idx0); pxz = st_load(xz + idx0); pxi = out[idx0];
    }
    xbar(ctr, GBLK);   // one-time: init visible before anyone polls

    // staging assignment: lane loads 2 adjacent slots of wave's 32-slot
    // window (per its batch), rotated by gb to spread LLC banks.
    const int b_ld = lane >> 4;
    const int s_rot = (((lane & 15) + (gb & 15)) * 2) & 31;   // even, in [0,32)
    const int ps_w = PS(s_rot);                               // padded write slot

    for (int t = 0; t < TT; ++t) {
        // ---- stage h_t: poll own k-slice until non-poison, wave-local sync ----
        {
            const f32x4* p = (const f32x4*)hbuf + (size_t)(t & 3) * 4096
                             + group * 1024 + b_ld * 256 + wv * 32 + s_rot;
            f32x4 va, vb;
            for (;;) {
                llc_load(va, p); llc_load(vb, p + 1); llc_drain();
                if (ok4(va) && ok4(vb)) break;
                __builtin_amdgcn_s_sleep(1);
            }
            hsx[wv][b_ld][ps_w]     = va;
            hsx[wv][b_ld][ps_w + 1] = vb;
            asm volatile("s_waitcnt lgkmcnt(0)" ::: "memory");  // wave-local LDS visibility
            __builtin_amdgcn_sched_barrier(0);
        }

        // ---- early re-poison B(t+2) (validated R6/R9; acks under compute) ----
        if (tid < 64 && t + 2 < TT) {
            __hip_atomic_store(hbuf + (size_t)((t + 2) & 3) * 16384
                               + group * (BPG * HH) + tb4 * HH + coln,
                               pzf, __ATOMIC_RELAXED, __HIP_MEMORY_SCOPE_AGENT);
        }

        // ---- partial dots: 4 batches x 12 units x 8 k = 384 FMA/thread ----
        float pacc[4][12];
#pragma unroll
        for (int b = 0; b < 4; ++b)
#pragma unroll
            for (int u = 0; u < 12; ++u) pacc[b][u] = 0.f;

        const int ps_r = PS(2 * kslo);              // padded read slot (even)
#pragma unroll
        for (int b = 0; b < 4; ++b) {
            f32x4 ha = hsx[wv][b][ps_r];
            f32x4 hb = hsx[wv][b][ps_r + 1];
#pragma unroll
            for (int u = 0; u < 12; ++u) {
                float a = pacc[b][u];
                a = fmaf(ha[0], wreg[u][0], a);
                a = fmaf(ha[1], wreg[u][1], a);
                a = fmaf(ha[2], wreg[u][2], a);
                a = fmaf(ha[3], wreg[u][3], a);
                a = fmaf(hb[0], wreg[u][4], a);
                a = fmaf(hb[1], wreg[u][5], a);
                a = fmaf(hb[2], wreg[u][6], a);
                a = fmaf(hb[3], wreg[u][7], a);
                pacc[b][u] = a;
            }
        }

        // ---- reduce over kslo (16 lanes per row) ----
#pragma unroll
        for (int b = 0; b < 4; ++b)
#pragma unroll
            for (int u = 0; u < 12; ++u) pacc[b][u] = row16_allreduce(pacc[b][u]);

        if (kslo == 0) {
#pragma unroll
            for (int b = 0; b < 4; ++b)
#pragma unroll
                for (int u = 0; u < 12; ++u) red[t & 1][wv][cgg][b * 12 + u] = pacc[b][u];
        }
        __syncthreads();                 // S1: red@t ready (only barrier/step)

        // ---- elementwise GRU update (tail reads red directly; no combine) ----
        if (tid < 64) {
            float g3[3];
#pragma unroll
            for (int g = 0; g < 3; ++g) {
                int ugc = g * 16 + tc;              // [0,48)
                int cq = ugc / 12, u = ugc - cq * 12;
                float s = 0.f;
#pragma unroll
                for (int w = 0; w < 8; ++w) s += red[t & 1][w][cq][tb4 * 12 + u];
                g3[g] = s;
            }
            float r = 1.f / (1.f + expf(-(g3[0] + pxr)));
            float z = 1.f / (1.f + expf(-(g3[1] + pxz)));
            float cand = tanhf(fmaf(r, g3[2], pxi));
            float hnew = fmaf(z, hprev - cand, cand);         // z*h + (1-z)*cand
            hprev = hnew;                                     // carried in register
            // drain: orders the (long-acked) early poison before the h-store
            asm volatile("s_waitcnt vmcnt(0)" ::: "memory");
            __builtin_amdgcn_sched_barrier(0);
            if (t + 1 < TT) {
                __hip_atomic_store(hbuf + (size_t)((t + 1) & 3) * 16384
                                   + group * (BPG * HH) + tb4 * HH + coln,
                                   hnew, __ATOMIC_RELAXED, __HIP_MEMORY_SCOPE_AGENT);
            }
            size_t idx = (size_t)(tbg * TT + t) * HH + coln;
            out[idx] = hnew;
            // self-prefetch t+1 operands (off critical path; lands during next step)
            if (t + 1 < TT) {
                size_t idx2 = idx + HH;
                pxr = st_load(xr + idx2); pxz = st_load(xz + idx2); pxi = out[idx2];
            }
        }
        // no further barrier: waves proceed straight to polling h_{t+1}
    }
}

__global__ void sentinel_kernel(float* out) {
    if (threadIdx.x == 0 && blockIdx.x == 0) out[0] = 12345.0f;
}

// =====================================================================
extern "C" void kernel_launch(void* const* d_in, const int* in_sizes, int n_in,
                              void* d_out, int out_size, void* d_ws, size_t ws_size,
                              hipStream_t stream) {
    const float* x   = (const float*)d_in[0];
    const float* Wxr = (const float*)d_in[1];
    const float* Whr = (const float*)d_in[2];
    const float* br  = (const float*)d_in[3];
    const float* Wxz = (const float*)d_in[4];
    const float* Whz = (const float*)d_in[5];
    const float* bz  = (const float*)d_in[6];
    const float* Wi  = (const float*)d_in[7];
    const float* Wh  = (const float*)d_in[8];
    const float* bb  = (const float*)d_in[9];
    float* out = (float*)d_out;

    const size_t BTH = (size_t)BB * TT * HH;
    const size_t HBUF_ELTS = (size_t)4 * BB * HH;      // 4 rotating epochs
    const size_t BAR_BYTES = 4096;
    const size_t need_f32 = 2 * BTH * sizeof(float) + HBUF_ELTS * sizeof(float) + BAR_BYTES;
    const size_t need_b16 = 2 * BTH * sizeof(__hip_bfloat16) + HBUF_ELTS * sizeof(float) + BAR_BYTES;

    dim3 pgrid(HH / 64, (BB * TT) / 64);   // (16, 256)

    if (ws_size >= need_f32) {
        float* xr = (float*)d_ws;
        float* xz = xr + BTH;
        float* hb = xz + BTH;
        u32* bar = (u32*)(hb + HBUF_ELTS);
        proj_kernel<float><<<pgrid, 256, 0, stream>>>(x, Wxr, br, Wxz, bz, Wi, bb, xr, xz, out, bar);
        const float* xrc = xr; const float* xzc = xz;
        void* args[8] = {(void*)&xrc, (void*)&xzc, (void*)&Whr, (void*)&Whz,
                         (void*)&Wh, (void*)&out, (void*)&hb, (void*)&bar};
        hipLaunchCooperativeKernel((void*)scan_kernel<float>, dim3(256), dim3(512),
                                   args, 0, stream);
    } else if (ws_size >= need_b16) {
        __hip_bfloat16* xr = (__hip_bfloat16*)d_ws;
        __hip_bfloat16* xz = xr + BTH;
        float* hb = (float*)(xz + BTH);
        u32* bar = (u32*)(hb + HBUF_ELTS);
        proj_kernel<__hip_bfloat16><<<pgrid, 256, 0, stream>>>(x, Wxr, br, Wxz, bz, Wi, bb, xr, xz, out, bar);
        const __hip_bfloat16* xrc = xr; const __hip_bfloat16* xzc = xz;
        void* args[8] = {(void*)&xrc, (void*)&xzc, (void*)&Whr, (void*)&Whz,
                         (void*)&Wh, (void*)&out, (void*)&hb, (void*)&bar};
        hipLaunchCooperativeKernel((void*)scan_kernel<__hip_bfloat16>, dim3(256), dim3(512),
                                   args, 0, stream);
    } else {
        sentinel_kernel<<<1, 64, 0, stream>>>(out);
    }
}